// Round 1
// baseline (358.956 us; speedup 1.0000x reference)
//
#include <hip/hip_runtime.h>

// XingLoss: x_list (P=16384, N=1024, 2) f32, scale (int scalar).
// Per row p, per segment s in [0,256): uses points x[3s..3s+3].
//   v1 = x[3s+1]-x[3s]; v2 = x[3s+2]-x[3s+1]; v3 = x[3s+3]-x[3s+2]
//   direct = cross(v1,v2) >= 0   (norms positive -> sign of cross suffices)
//   sina   = cross(v1,v3) / (|v1||v3|)
//   term   = direct ? relu(-sina) : relu(sina)
// out = scale * sum(term) / (segn * P)   -- single f32 scalar.

#define N_PTS  1024
#define SEGN   (N_PTS / 4)          // 256
#define BLOCK  256                  // one block per row; thread s -> segment s

__global__ __launch_bounds__(BLOCK)
void xing_loss_kernel(const float* __restrict__ x,
                      const int*   __restrict__ scale_p,
                      float*       __restrict__ out,
                      int P)
{
    const int p = blockIdx.x;
    const int s = threadIdx.x;           // 0..255 == segment index

    const float2* row = reinterpret_cast<const float2*>(x) + (size_t)p * N_PTS;

    // 4 consecutive points; byte addr of a = 24*s -> 8B aligned (float2 ok).
    const float2 a = row[3 * s + 0];
    const float2 b = row[3 * s + 1];
    const float2 c = row[3 * s + 2];
    const float2 d = row[3 * s + 3];

    const float v1x = b.x - a.x, v1y = b.y - a.y;
    const float v2x = c.x - b.x, v2y = c.y - b.y;
    const float v3x = d.x - c.x, v3y = d.y - c.y;

    const float cross12 = v1x * v2y - v1y * v2x;
    const float cross13 = v1x * v3y - v1y * v3x;

    const float n1 = v1x * v1x + v1y * v1y;
    const float n3 = v3x * v3x + v3y * v3y;
    const float sina = cross13 * rsqrtf(n1 * n3);

    float term = (cross12 >= 0.0f) ? fmaxf(-sina, 0.0f) : fmaxf(sina, 0.0f);

    // Wave-64 shuffle reduction.
    #pragma unroll
    for (int off = 32; off > 0; off >>= 1)
        term += __shfl_down(term, off, 64);

    __shared__ float wsum[BLOCK / 64];
    const int lane = threadIdx.x & 63;
    const int wid  = threadIdx.x >> 6;
    if (lane == 0) wsum[wid] = term;
    __syncthreads();

    if (threadIdx.x == 0) {
        float block_sum = 0.0f;
        #pragma unroll
        for (int w = 0; w < BLOCK / 64; ++w) block_sum += wsum[w];
        const float inv = (float)(*scale_p) / ((float)SEGN * (float)P);
        atomicAdd(out, block_sum * inv);
    }
}

extern "C" void kernel_launch(void* const* d_in, const int* in_sizes, int n_in,
                              void* d_out, int out_size, void* d_ws, size_t ws_size,
                              hipStream_t stream)
{
    const float* x       = (const float*)d_in[0];
    const int*   scale_p = (const int*)d_in[1];
    float*       out     = (float*)d_out;

    const int P = in_sizes[0] / (N_PTS * 2);   // 16384

    // d_out is re-poisoned to 0xAA before every timed launch; zero it.
    hipMemsetAsync(out, 0, sizeof(float), stream);

    xing_loss_kernel<<<P, BLOCK, 0, stream>>>(x, scale_p, out, P);
}

// Round 2
// 182.407 us; speedup vs baseline: 1.9679x; 1.9679x over previous
//
#include <hip/hip_runtime.h>

// XingLoss: x_list (P=16384, N=1024, 2) f32, scale (int scalar).
// Per row p, per segment s in [0,256): uses points x[3s..3s+3] (max idx 768).
//   v1 = x[3s+1]-x[3s]; v2 = x[3s+2]-x[3s+1]; v3 = x[3s+3]-x[3s+2]
//   direct = cross(v1,v2) >= 0   (norms positive -> sign of cross suffices)
//   sina   = cross(v1,v3) / (|v1||v3|)
//   term   = direct ? relu(-sina) : relu(sina)
// out = scale * sum(term) / (segn * P)   -- single f32 scalar.
//
// R1 -> R2: 215 us with HBM 3%, VALU 3% = latency-bound, not throughput.
// Suspected 16384 same-address atomicAdds serializing at L2 (~13ns each
// ~= 214us). Replaced with per-block partials in d_ws + tiny reduce
// kernel. Also: stage row prefix into LDS via coalesced float4 (old path
// had stride-24B dwordx2 loads spanning 24 lines per instruction).

#define N_PTS     1024
#define SEGN      (N_PTS / 4)        // 256
#define BLOCK     256                // one block per row; thread s -> segment s
#define ROW_F4    385                // ceil(1540 floats / 4): floats [0,1540) cover pts 0..768

__global__ __launch_bounds__(BLOCK)
void xing_partial_kernel(const float* __restrict__ x,
                         float*       __restrict__ partial)
{
    const int p = blockIdx.x;
    const int t = threadIdx.x;

    __shared__ float rowf[ROW_F4 * 4];   // 1540 floats = 6160 B

    // Coalesced float4 stage of the used prefix (row base is 8KB-aligned).
    const float4* src = reinterpret_cast<const float4*>(x + (size_t)p * (N_PTS * 2));
    float4* dst = reinterpret_cast<float4*>(rowf);
    dst[t] = src[t];
    if (t < ROW_F4 - BLOCK) dst[BLOCK + t] = src[BLOCK + t];
    __syncthreads();

    // Segment s uses floats 6s..6s+7 (points 3s..3s+3), 8B-aligned in LDS.
    const float2* pts = reinterpret_cast<const float2*>(rowf);
    const float2 a = pts[3 * t + 0];
    const float2 b = pts[3 * t + 1];
    const float2 c = pts[3 * t + 2];
    const float2 d = pts[3 * t + 3];

    const float v1x = b.x - a.x, v1y = b.y - a.y;
    const float v2x = c.x - b.x, v2y = c.y - b.y;
    const float v3x = d.x - c.x, v3y = d.y - c.y;

    const float cross12 = v1x * v2y - v1y * v2x;
    const float cross13 = v1x * v3y - v1y * v3x;

    const float n1 = v1x * v1x + v1y * v1y;
    const float n3 = v3x * v3x + v3y * v3y;
    const float sina = cross13 * rsqrtf(n1 * n3);

    float term = (cross12 >= 0.0f) ? fmaxf(-sina, 0.0f) : fmaxf(sina, 0.0f);

    // Wave-64 shuffle reduction.
    #pragma unroll
    for (int off = 32; off > 0; off >>= 1)
        term += __shfl_down(term, off, 64);

    __shared__ float wsum[BLOCK / 64];
    const int lane = t & 63;
    const int wid  = t >> 6;
    if (lane == 0) wsum[wid] = term;
    __syncthreads();

    if (t == 0) {
        // One coalesced store per block; no atomics anywhere.
        partial[p] = (wsum[0] + wsum[1]) + (wsum[2] + wsum[3]);
    }
}

// Reduce P partials -> single scalar.  P*4B = 64KB, trivially fast.
__global__ __launch_bounds__(BLOCK)
void xing_reduce_kernel(const float* __restrict__ partial,
                        const int*   __restrict__ scale_p,
                        float*       __restrict__ out,
                        int P)
{
    const int t = threadIdx.x;
    const float4* pf4 = reinterpret_cast<const float4*>(partial);
    const int nf4 = P / 4;   // 4096

    float sum = 0.0f;
    for (int i = t; i < nf4; i += BLOCK) {
        float4 v = pf4[i];
        sum += (v.x + v.y) + (v.z + v.w);
    }

    #pragma unroll
    for (int off = 32; off > 0; off >>= 1)
        sum += __shfl_down(sum, off, 64);

    __shared__ float wsum[BLOCK / 64];
    const int lane = t & 63;
    const int wid  = t >> 6;
    if (lane == 0) wsum[wid] = sum;
    __syncthreads();

    if (t == 0) {
        const float total = (wsum[0] + wsum[1]) + (wsum[2] + wsum[3]);
        out[0] = total * (float)(*scale_p) / ((float)SEGN * (float)P);
    }
}

extern "C" void kernel_launch(void* const* d_in, const int* in_sizes, int n_in,
                              void* d_out, int out_size, void* d_ws, size_t ws_size,
                              hipStream_t stream)
{
    const float* x       = (const float*)d_in[0];
    const int*   scale_p = (const int*)d_in[1];
    float*       out     = (float*)d_out;
    float*       partial = (float*)d_ws;

    const int P = in_sizes[0] / (N_PTS * 2);   // 16384

    xing_partial_kernel<<<P, BLOCK, 0, stream>>>(x, partial);
    xing_reduce_kernel<<<1, BLOCK, 0, stream>>>(partial, scale_p, out, P);
}